// Round 16
// baseline (735.225 us; speedup 1.0000x reference)
//
#include <hip/hip_runtime.h>
#include <cstdint>
#include <cstddef>
#include <cmath>

#define B_N   32768
#define D_DIM 512
#define NC_N  64
#define NTRI  2016      /* packed upper-triangle skew columns (i<j) */
#define NP    2176      /* 2016 tri + 64 w_z + 8 g_u + 8 g_v + 80 pad (17*128) */
#define Q0    2016
#define U0    2080
#define V0    2088
#define KP    1536      /* [zh|zh|zl] . [wh|wl|wh] f16 split, K=3*512 */
#define KT_N  24        /* KP/64 */
#define TEPS  1e-3f
#define SC1   0x1.0p-22f  /* undo 2^11 * 2^11 input scaling */

typedef unsigned short u16;
typedef _Float16 f16;
typedef __attribute__((ext_vector_type(8))) _Float16 f16x8;
typedef __attribute__((ext_vector_type(4))) float f32x4;
typedef __attribute__((ext_vector_type(2))) float f32x2;

__device__ __forceinline__ u16 h_of(float x) { f16 h = (f16)x; return *reinterpret_cast<u16*>(&h); }
__device__ __forceinline__ float f_of_h(u16 u) { f16 h = *reinterpret_cast<f16*>(&u); return (float)h; }
__device__ __forceinline__ float rdlane(float x, int k) {
    return __int_as_float(__builtin_amdgcn_readlane(__float_as_int(x), k));
}
__device__ __forceinline__ float frcp(float x) {
    float r = __builtin_amdgcn_rcpf(x);
    return r * fmaf(-x, r, 2.0f);
}
__device__ __forceinline__ void split2(float x, u16& h, u16& l) {
    float s = x * 2048.0f;           // exact
    h = h_of(s);
    l = h_of(s - f_of_h(h));
}

// ---------------- prep: B' rows -> [NP][1536] f16 = [wh|wl|wh]
// rows 0..2015 (packed pair p <-> (i<j)): 0.25*(w_t[j*64+i] - w_t[i*64+j]).
// rows 2016..2079: w_z ; 2080..2087: g_u ; 2088..2095: g_v ; rest 0.
__global__ __launch_bounds__(256) void prep_w_kernel(
    const float* __restrict__ wt, const float* __restrict__ wz,
    const float* __restrict__ gu, const float* __restrict__ gv,
    u16* __restrict__ dst)
{
    int t = blockIdx.x * 256 + threadIdx.x;
    if (t >= NP * 128) return;
    int row = t >> 7;
    int c4  = (t & 127) << 2;
    float4 v = make_float4(0.f, 0.f, 0.f, 0.f);
    if (row < NTRI) {
        int p = row;
        int i = (int)((127.0 - sqrt(16129.0 - 8.0 * (double)p)) * 0.5);
        if (i < 0) i = 0; if (i > 62) i = 62;
        while (i > 0 && (i * (127 - i)) / 2 > p) --i;
        while (((i + 1) * (126 - i)) / 2 <= p) ++i;
        int j = p - (i * (127 - i)) / 2 + i + 1;
        float4 a = *(const float4*)(wt + (size_t)(j * 64 + i) * 512 + c4);
        float4 b = *(const float4*)(wt + (size_t)(i * 64 + j) * 512 + c4);
        v.x = 0.25f * (a.x - b.x);
        v.y = 0.25f * (a.y - b.y);
        v.z = 0.25f * (a.z - b.z);
        v.w = 0.25f * (a.w - b.w);
    }
    else if (row < U0)        v = *(const float4*)(wz + (size_t)(row - Q0) * 512 + c4);
    else if (row < V0)        v = *(const float4*)(gu + (size_t)(row - U0) * 512 + c4);
    else if (row < V0 + 8)    v = *(const float4*)(gv + (size_t)(row - V0) * 512 + c4);
    ushort4 hv, lv;
    split2(v.x, hv.x, lv.x); split2(v.y, hv.y, lv.y);
    split2(v.z, hv.z, lv.z); split2(v.w, hv.w, lv.w);
    u16* base = dst + (size_t)row * KP + c4;
    *(ushort4*)(base)        = hv;
    *(ushort4*)(base + 512)  = lv;
    *(ushort4*)(base + 1024) = hv;
}

// ---------------- prep: z chunk -> [CB][1536] f16 = [zh|zh|zl]
__global__ __launch_bounds__(256) void prep_z_kernel(
    const float* __restrict__ z, u16* __restrict__ dst, int chunkStart, int CB)
{
    int t = blockIdx.x * 256 + threadIdx.x;
    if (t >= CB * 128) return;
    int row = t >> 7;
    int c4  = (t & 127) << 2;
    float4 v = *(const float4*)(z + (size_t)(chunkStart + row) * 512 + c4);
    ushort4 hv, lv;
    split2(v.x, hv.x, lv.x); split2(v.y, hv.y, lv.y);
    split2(v.z, hv.z, lv.z); split2(v.w, hv.w, lv.w);
    u16* base = dst + (size_t)row * KP + c4;
    *(ushort4*)(base)        = hv;
    *(ushort4*)(base + 512)  = hv;
    *(ushort4*)(base + 1024) = lv;
}

// ---------------- GEMM: C[CB][NP] f32 = (A[CB][KP] * B[NP][KP]^T) * 2^-22
// 256(M)x128(N) tile, 512 thr / 8 waves (4M x 2N), BK=64. Per-wave work is the
// r9-PROVEN 64x64 = 4x4 frags of 16x16x32 (same layouts, acc=64 VGPR). vs the
// 128^2 tile: barriers/flop halve, staging bytes/flop -25%, B re-fetch halves.
// LDS 48KB -> 3 blocks x 8 waves = 24 waves/CU (MORE than 128^2's 20 — avoids
// the m132 LDS-occupancy trap). global_load_lds(16B), bijective XCD swizzle
// (grid 17x128 = 2176 % 8 == 0), non-temporal C stores.
__global__ __launch_bounds__(512) void gemm_kernel(
    const u16* __restrict__ A, const u16* __restrict__ Bw, float* __restrict__ C)
{
    __shared__ alignas(16) u16 As[256 * 64];   // 32 KB
    __shared__ alignas(16) u16 Bs[128 * 64];   // 16 KB
    const int t    = threadIdx.x;
    const int lane = t & 63;
    const int w    = t >> 6;          // 0..7
    const int wr   = w >> 1;          // 0..3 (M)
    const int wc   = w & 1;           // 0..1 (N)

    const int nwg = gridDim.x * gridDim.y;
    int flat = blockIdx.y * gridDim.x + blockIdx.x;
    if ((nwg & 7) == 0) {
        const int cpx = nwg >> 3;
        flat = (flat & 7) * cpx + (flat >> 3);
    }
    const int bx = flat % gridDim.x;  // N-dir (17)
    const int by = flat / gridDim.x;  // M-dir
    const size_t m0 = (size_t)by * 256;
    const size_t n0 = (size_t)bx * 128;

    // staging: per stmt, 512 threads cover 64 rows x 128 B; dest = wave-uniform
    // base + lane*16 (linear: (lane>>3)*128 + (lane&7)*16 == lane*16).
    const int rT  = t >> 3;           // 0..63
    const int cTb = (t & 7) * 16;     // byte col
    const char* Ab = (const char*)A  + (m0 + rT) * (size_t)(KP * 2) + cTb;
    const char* Bb = (const char*)Bw + (n0 + rT) * (size_t)(KP * 2) + cTb;
    char* AsB = (char*)&As[0];
    char* BsB = (char*)&Bs[0];
    const int dstoff = rT * 128 + cTb;

    f32x4 acc[4][4];
    #pragma unroll
    for (int i = 0; i < 4; ++i)
        #pragma unroll
        for (int j = 0; j < 4; ++j)
            acc[i][j] = (f32x4){0.f, 0.f, 0.f, 0.f};

    const int lr = lane & 15;
    const int lk = (lane >> 4) * 8;

    #pragma unroll 1
    for (int kt = 0; kt < KT_N; ++kt) {
        __syncthreads();
        const size_t koff = (size_t)kt * 128;
        #pragma unroll
        for (int h = 0; h < 4; ++h) {     // A: 4 x 64 rows = 256
            __builtin_amdgcn_global_load_lds(
                (const __attribute__((address_space(1))) unsigned int*)(Ab + (size_t)h * (64 * KP * 2) + koff),
                (__attribute__((address_space(3))) unsigned int*)(AsB + h * 8192 + dstoff),
                16, 0, 0);
        }
        #pragma unroll
        for (int h = 0; h < 2; ++h) {     // B: 2 x 64 rows = 128
            __builtin_amdgcn_global_load_lds(
                (const __attribute__((address_space(1))) unsigned int*)(Bb + (size_t)h * (64 * KP * 2) + koff),
                (__attribute__((address_space(3))) unsigned int*)(BsB + h * 8192 + dstoff),
                16, 0, 0);
        }
        asm volatile("s_waitcnt vmcnt(0)" ::: "memory");
        __syncthreads();
        #pragma unroll
        for (int kk = 0; kk < 64; kk += 32) {
            f16x8 af[4], bf[4];
            #pragma unroll
            for (int i = 0; i < 4; ++i) {
                af[i] = *(const f16x8*)&As[(wr * 64 + i * 16 + lr) * 64 + kk + lk];
                bf[i] = *(const f16x8*)&Bs[(wc * 64 + i * 16 + lr) * 64 + kk + lk];
            }
            #pragma unroll
            for (int i = 0; i < 4; ++i)
                #pragma unroll
                for (int j = 0; j < 4; ++j)
                    acc[i][j] = __builtin_amdgcn_mfma_f32_16x16x32_f16(af[i], bf[j], acc[i][j], 0, 0, 0);
        }
    }
    const int fq = lane >> 4;
    const int fr = lane & 15;
    #pragma unroll
    for (int i = 0; i < 4; ++i) {
        #pragma unroll
        for (int j = 0; j < 4; ++j) {
            size_t crow = m0 + (size_t)(wr * 64 + i * 16 + fq * 4);
            size_t ccol = n0 + (size_t)(wc * 64 + j * 16 + fr);
            #pragma unroll
            for (int r = 0; r < 4; ++r)
                __builtin_nontemporal_store(acc[i][j][r] * SC1, &C[(crow + r) * NP + ccol]);
        }
    }
}

// ---------------- per-sample Cayley solve + router (r15-proven body)
// 4 samples per 256-thread block (1 wave each). LDS-staged packed triangle,
// per-row gather, packed-f32 Gauss-Jordan, ONE f32-residual refinement,
// v = 2c*y - q, scores = cq @ v, softmax/argmax.
__global__ __launch_bounds__(256) void solve_kernel(
    const float* __restrict__ z, const float* __restrict__ bz,
    const float* __restrict__ gout, const float* __restrict__ cq,
    const float* __restrict__ G, float* __restrict__ rw, float* __restrict__ kc,
    int chunkStart)
{
    const int tid  = threadIdx.x;
    const int lane = tid & 63;
    const int smp  = tid >> 6;
    const int sl   = (blockIdx.x << 2) + smp;
    const size_t s = (size_t)chunkStart + sl;
    const float c  = 1.0f + TEPS;

    __shared__ alignas(16) float Vs[4][2048];

    const float* Grow = G + (size_t)sl * NP;

    const float4* G4 = (const float4*)Grow;
    float4* Vw = (float4*)&Vs[smp][0];
    #pragma unroll
    for (int it = 0; it < 8; ++it) {
        int idx = it * 64 + lane;
        if (idx < NTRI / 4) Vw[idx] = G4[idx];
    }

    const float4* zr = (const float4*)(z + s * 512);
    float4 za = zr[lane];
    float4 zb = zr[64 + lane];
    float r2 = za.x * za.x + za.y * za.y + za.z * za.z + za.w * za.w
             + zb.x * zb.x + zb.y * zb.y + zb.z * zb.z + zb.w * zb.w;
    #pragma unroll
    for (int o = 32; o; o >>= 1) r2 += __shfl_xor(r2, o);

    float qv = bz[lane] + Grow[Q0 + lane];
    #pragma unroll
    for (int r = 0; r < 8; ++r) {
        float a = Grow[U0 + r];
        float b = Grow[V0 + r];
        qv = fmaf(a * b, gout[r * 64 + lane], qv);
    }
    const float qorig = qv;

    const int ibase = (lane * (127 - lane)) / 2 - lane - 1;
    f32x2 m2[32];
    #pragma unroll
    for (int j = 0; j < 64; ++j) {
        const int jbase = (j * (127 - j)) / 2 - j - 1;
        int addr = (j > lane) ? (ibase + j) : (jbase + lane);
        addr = (j == lane) ? 0 : addr;
        float v = Vs[smp][addr];
        float val = (j > lane) ? v : -v;
        val = (j == lane) ? 0.0f : val;
        if (j & 1) m2[j >> 1].y = val; else m2[j >> 1].x = val;
    }

    float myinv = 0.0f;
    #pragma unroll
    for (int k = 0; k < 64; ++k) {
        const int kp = k >> 1;
        const float mk = (k & 1) ? m2[kp].y : m2[kp].x;
        float piv = rdlane(mk, k) + c;
        float inv = frcp(piv);
        bool isk = (lane == k);
        float f = isk ? 0.0f : mk * inv;
        myinv = isk ? inv : myinv;
        const float nf = -f;
        const f32x2 nf2 = {nf, nf};
        qv = fmaf(nf, rdlane(qv, k), qv);
        if ((k & 1) == 0)
            m2[kp].y = fmaf(nf, rdlane(m2[kp].y, k), m2[kp].y);
        #pragma unroll
        for (int p = kp + 1; p < 32; ++p) {
            f32x2 bc;
            bc.x = rdlane(m2[p].x, k);
            bc.y = rdlane(m2[p].y, k);
            m2[p] = __builtin_elementwise_fma(nf2, bc, m2[p]);
        }
        if (k & 1) m2[kp].y = f; else m2[kp].x = f;
    }
    float y = qv * myinv;

    // ---- one refinement step, f32 residual: r = (q - c*y) - S'*y
    float rf = fmaf(-c, y, qorig);
    #pragma unroll
    for (int j = 0; j < 64; ++j) {
        const int jbase = (j * (127 - j)) / 2 - j - 1;
        int addr = (j > lane) ? (ibase + j) : (jbase + lane);
        addr = (j == lane) ? 0 : addr;
        float v = Vs[smp][addr];
        float val = (j > lane) ? v : -v;
        val = (j == lane) ? 0.0f : val;
        rf = fmaf(-val, rdlane(y, j), rf);
    }
    #pragma unroll
    for (int k = 0; k < 64; ++k) {
        const float mk = (k & 1) ? m2[k >> 1].y : m2[k >> 1].x;
        rf = fmaf(-mk, rdlane(rf, k), rf);
    }
    y = fmaf(rf, myinv, y);

    const float v = 2.0f * c * y - qorig;

    float sc = 0.0f;
    const float4* cr = (const float4*)(cq + (size_t)lane * 64);
    #pragma unroll
    for (int j4 = 0; j4 < 16; ++j4) {
        float4 c4 = cr[j4];
        sc = fmaf(c4.x, rdlane(v, 4 * j4 + 0), sc);
        sc = fmaf(c4.y, rdlane(v, 4 * j4 + 1), sc);
        sc = fmaf(c4.z, rdlane(v, 4 * j4 + 2), sc);
        sc = fmaf(c4.w, rdlane(v, 4 * j4 + 3), sc);
    }

    float denom = fmaxf(1.0f - r2, 1e-3f);
    float tau   = fmaxf(4.0f * denom, 0.01f);
    float logit = sc * frcp(tau);
    float mx = logit;
    #pragma unroll
    for (int o = 32; o; o >>= 1) mx = fmaxf(mx, __shfl_xor(mx, o));
    float e = __expf(logit - mx);
    float sum = e;
    #pragma unroll
    for (int o = 32; o; o >>= 1) sum += __shfl_xor(sum, o);
    rw[s * 64 + lane] = e * frcp(sum);

    unsigned long long bal = __ballot(logit == mx);
    if (lane == 0) kc[s] = (float)(__ffsll(bal) - 1);
}

// ---------------- host orchestration (single CB=32768 chunk)
extern "C" void kernel_launch(void* const* d_in, const int* in_sizes, int n_in,
                              void* d_out, int out_size, void* d_ws, size_t ws_size,
                              hipStream_t stream)
{
    const float* z    = (const float*)d_in[0];
    const float* wz   = (const float*)d_in[1];
    const float* bz   = (const float*)d_in[2];
    const float* gout = (const float*)d_in[3];
    const float* gu   = (const float*)d_in[4];
    const float* gv   = (const float*)d_in[5];
    const float* cq   = (const float*)d_in[6];
    const float* wt   = (const float*)d_in[7];

    float* rw = (float*)d_out;
    float* kc = rw + (size_t)B_N * NC_N;

    const size_t whl_b = (size_t)NP * KP * 2;   // ~6.7 MB
    int CB = 256;
    const int cands[8] = {32768, 16384, 8192, 4096, 2048, 1024, 512, 256};
    for (int i = 0; i < 8; ++i) {
        size_t need = whl_b + (size_t)cands[i] * ((size_t)KP * 2 + (size_t)NP * 4);
        if (need <= ws_size) { CB = cands[i]; break; }
    }

    u16*   w_hl = (u16*)d_ws;
    u16*   z_hl = (u16*)((char*)d_ws + whl_b);
    float* G    = (float*)((char*)d_ws + whl_b + (size_t)CB * KP * 2);

    prep_w_kernel<<<NP / 2, 256, 0, stream>>>(wt, wz, gu, gv, w_hl);
    for (int cs = 0; cs < B_N; cs += CB) {
        prep_z_kernel<<<CB / 2, 256, 0, stream>>>(z, z_hl, cs, CB);
        gemm_kernel<<<dim3(NP / 128, CB / 256), 512, 0, stream>>>(z_hl, w_hl, G);
        solve_kernel<<<CB / 4, 256, 0, stream>>>(z, bz, gout, cq, G, rw, kc, cs);
    }
}

// Round 17
// 690.922 us; speedup vs baseline: 1.0641x; 1.0641x over previous
//
#include <hip/hip_runtime.h>
#include <cstdint>
#include <cstddef>
#include <cmath>

#define B_N   32768
#define D_DIM 512
#define NC_N  64
#define NTRI  2016      /* packed upper-triangle skew columns (i<j) */
#define NP    2176      /* 2016 tri + 64 w_z + 8 g_u + 8 g_v + 80 pad (17*128) */
#define Q0    2016
#define U0    2080
#define V0    2088
#define KP    1536      /* [zh|zh|zl] . [wh|wl|wh] f16 split, K=3*512 */
#define KT_N  24        /* KP/64 */
#define TEPS  1e-3f
#define SC1   0x1.0p-22f  /* undo 2^11 * 2^11 input scaling */

typedef unsigned short u16;
typedef _Float16 f16;
typedef __attribute__((ext_vector_type(8))) _Float16 f16x8;
typedef __attribute__((ext_vector_type(4))) float f32x4;
typedef __attribute__((ext_vector_type(2))) float f32x2;

__device__ __forceinline__ u16 h_of(float x) { f16 h = (f16)x; return *reinterpret_cast<u16*>(&h); }
__device__ __forceinline__ float f_of_h(u16 u) { f16 h = *reinterpret_cast<f16*>(&u); return (float)h; }
__device__ __forceinline__ float rdlane(float x, int k) {
    return __int_as_float(__builtin_amdgcn_readlane(__float_as_int(x), k));
}
__device__ __forceinline__ float frcp(float x) {
    float r = __builtin_amdgcn_rcpf(x);
    return r * fmaf(-x, r, 2.0f);
}
__device__ __forceinline__ void split2(float x, u16& h, u16& l) {
    float s = x * 2048.0f;           // exact
    h = h_of(s);
    l = h_of(s - f_of_h(h));
}

// ---------------- prep: B' rows -> [NP][1536] f16 = [wh|wl|wh]
// rows 0..2015 (packed pair p <-> (i<j)): 0.25*(w_t[j*64+i] - w_t[i*64+j]).
// rows 2016..2079: w_z ; 2080..2087: g_u ; 2088..2095: g_v ; rest 0.
__global__ __launch_bounds__(256) void prep_w_kernel(
    const float* __restrict__ wt, const float* __restrict__ wz,
    const float* __restrict__ gu, const float* __restrict__ gv,
    u16* __restrict__ dst)
{
    int t = blockIdx.x * 256 + threadIdx.x;
    if (t >= NP * 128) return;
    int row = t >> 7;
    int c4  = (t & 127) << 2;
    float4 v = make_float4(0.f, 0.f, 0.f, 0.f);
    if (row < NTRI) {
        int p = row;
        int i = (int)((127.0 - sqrt(16129.0 - 8.0 * (double)p)) * 0.5);
        if (i < 0) i = 0; if (i > 62) i = 62;
        while (i > 0 && (i * (127 - i)) / 2 > p) --i;
        while (((i + 1) * (126 - i)) / 2 <= p) ++i;
        int j = p - (i * (127 - i)) / 2 + i + 1;
        float4 a = *(const float4*)(wt + (size_t)(j * 64 + i) * 512 + c4);
        float4 b = *(const float4*)(wt + (size_t)(i * 64 + j) * 512 + c4);
        v.x = 0.25f * (a.x - b.x);
        v.y = 0.25f * (a.y - b.y);
        v.z = 0.25f * (a.z - b.z);
        v.w = 0.25f * (a.w - b.w);
    }
    else if (row < U0)        v = *(const float4*)(wz + (size_t)(row - Q0) * 512 + c4);
    else if (row < V0)        v = *(const float4*)(gu + (size_t)(row - U0) * 512 + c4);
    else if (row < V0 + 8)    v = *(const float4*)(gv + (size_t)(row - V0) * 512 + c4);
    ushort4 hv, lv;
    split2(v.x, hv.x, lv.x); split2(v.y, hv.y, lv.y);
    split2(v.z, hv.z, lv.z); split2(v.w, hv.w, lv.w);
    u16* base = dst + (size_t)row * KP + c4;
    *(ushort4*)(base)        = hv;
    *(ushort4*)(base + 512)  = lv;
    *(ushort4*)(base + 1024) = hv;
}

// ---------------- prep: z chunk -> [CB][1536] f16 = [zh|zh|zl]
__global__ __launch_bounds__(256) void prep_z_kernel(
    const float* __restrict__ z, u16* __restrict__ dst, int chunkStart, int CB)
{
    int t = blockIdx.x * 256 + threadIdx.x;
    if (t >= CB * 128) return;
    int row = t >> 7;
    int c4  = (t & 127) << 2;
    float4 v = *(const float4*)(z + (size_t)(chunkStart + row) * 512 + c4);
    ushort4 hv, lv;
    split2(v.x, hv.x, lv.x); split2(v.y, hv.y, lv.y);
    split2(v.z, hv.z, lv.z); split2(v.w, hv.w, lv.w);
    u16* base = dst + (size_t)row * KP + c4;
    *(ushort4*)(base)        = hv;
    *(ushort4*)(base + 512)  = hv;
    *(ushort4*)(base + 1024) = lv;
}

// ---------------- GEMM: C[CB][NP] f32 = (A[CB][KP] * B[NP][KP]^T) * 2^-22
// r9-proven 128x128 tile, BK=64, 4 waves (2x2), 16x16x32 f16 MFMA,
// global_load_lds(16B), bijective XCD swizzle, non-temporal C stores.
// (Shape-saturated: 8-phase 256^2 (r10), 256x128 (r16), CB-chunking (r14),
// solve-fusion (r13) all regressed — this is the local optimum for thin-K.)
__global__ __launch_bounds__(256) void gemm_kernel(
    const u16* __restrict__ A, const u16* __restrict__ Bw, float* __restrict__ C)
{
    __shared__ alignas(16) u16 As[128 * 64];
    __shared__ alignas(16) u16 Bs[128 * 64];
    const int t    = threadIdx.x;
    const int lane = t & 63;
    const int w    = t >> 6;
    const int wr   = w >> 1, wc = w & 1;

    const int nwg = gridDim.x * gridDim.y;
    int flat = blockIdx.y * gridDim.x + blockIdx.x;
    if ((nwg & 7) == 0) {
        const int cpx = nwg >> 3;
        flat = (flat & 7) * cpx + (flat >> 3);
    }
    const int bx = flat % gridDim.x;
    const int by = flat / gridDim.x;
    const size_t m0 = (size_t)by * 128;
    const size_t n0 = (size_t)bx * 128;

    const char* Ab = (const char*)A  + (m0 + (size_t)(t >> 3)) * (KP * 2) + (size_t)(t & 7) * 16;
    const char* Bb = (const char*)Bw + (n0 + (size_t)(t >> 3)) * (KP * 2) + (size_t)(t & 7) * 16;
    char* AsB = (char*)&As[0];
    char* BsB = (char*)&Bs[0];

    f32x4 acc[4][4];
    #pragma unroll
    for (int i = 0; i < 4; ++i)
        #pragma unroll
        for (int j = 0; j < 4; ++j)
            acc[i][j] = (f32x4){0.f, 0.f, 0.f, 0.f};

    const int lr = lane & 15;
    const int lk = (lane >> 4) * 8;

    #pragma unroll 1
    for (int kt = 0; kt < KT_N; ++kt) {
        __syncthreads();
        const size_t koff = (size_t)kt * 128;
        #pragma unroll
        for (int cc = 0; cc < 4; ++cc) {
            __builtin_amdgcn_global_load_lds(
                (const __attribute__((address_space(1))) unsigned int*)(Ab + (size_t)cc * (32 * KP * 2) + koff),
                (__attribute__((address_space(3))) unsigned int*)(AsB + cc * 4096 + w * 1024),
                16, 0, 0);
            __builtin_amdgcn_global_load_lds(
                (const __attribute__((address_space(1))) unsigned int*)(Bb + (size_t)cc * (32 * KP * 2) + koff),
                (__attribute__((address_space(3))) unsigned int*)(BsB + cc * 4096 + w * 1024),
                16, 0, 0);
        }
        asm volatile("s_waitcnt vmcnt(0)" ::: "memory");
        __syncthreads();
        #pragma unroll
        for (int kk = 0; kk < 64; kk += 32) {
            f16x8 af[4], bf[4];
            #pragma unroll
            for (int i = 0; i < 4; ++i) {
                af[i] = *(const f16x8*)&As[(wr * 64 + i * 16 + lr) * 64 + kk + lk];
                bf[i] = *(const f16x8*)&Bs[(wc * 64 + i * 16 + lr) * 64 + kk + lk];
            }
            #pragma unroll
            for (int i = 0; i < 4; ++i)
                #pragma unroll
                for (int j = 0; j < 4; ++j)
                    acc[i][j] = __builtin_amdgcn_mfma_f32_16x16x32_f16(af[i], bf[j], acc[i][j], 0, 0, 0);
        }
    }
    const int fq = lane >> 4;
    const int fr = lane & 15;
    #pragma unroll
    for (int i = 0; i < 4; ++i) {
        #pragma unroll
        for (int j = 0; j < 4; ++j) {
            size_t crow = m0 + (size_t)(wr * 64 + i * 16 + fq * 4);
            size_t ccol = n0 + (size_t)(wc * 64 + j * 16 + fr);
            #pragma unroll
            for (int r = 0; r < 4; ++r)
                __builtin_nontemporal_store(acc[i][j][r] * SC1, &C[(crow + r) * NP + ccol]);
        }
    }
}

// ---------------- per-sample Cayley solve + router (r15-proven body)
// 4 samples per 256-thread block (1 wave each). LDS-staged packed triangle,
// per-row gather, packed-f32 Gauss-Jordan, ONE f32-residual refinement
// (f64 dropped: unrefined y err ~1e-5 rel; f32 residual recovers to ~1e-7,
// 40x margin on the argmax logit budget), v = 2c*y - q, softmax/argmax.
__global__ __launch_bounds__(256) void solve_kernel(
    const float* __restrict__ z, const float* __restrict__ bz,
    const float* __restrict__ gout, const float* __restrict__ cq,
    const float* __restrict__ G, float* __restrict__ rw, float* __restrict__ kc,
    int chunkStart)
{
    const int tid  = threadIdx.x;
    const int lane = tid & 63;
    const int smp  = tid >> 6;
    const int sl   = (blockIdx.x << 2) + smp;
    const size_t s = (size_t)chunkStart + sl;
    const float c  = 1.0f + TEPS;

    __shared__ alignas(16) float Vs[4][2048];

    const float* Grow = G + (size_t)sl * NP;

    const float4* G4 = (const float4*)Grow;
    float4* Vw = (float4*)&Vs[smp][0];
    #pragma unroll
    for (int it = 0; it < 8; ++it) {
        int idx = it * 64 + lane;
        if (idx < NTRI / 4) Vw[idx] = G4[idx];
    }

    const float4* zr = (const float4*)(z + s * 512);
    float4 za = zr[lane];
    float4 zb = zr[64 + lane];
    float r2 = za.x * za.x + za.y * za.y + za.z * za.z + za.w * za.w
             + zb.x * zb.x + zb.y * zb.y + zb.z * zb.z + zb.w * zb.w;
    #pragma unroll
    for (int o = 32; o; o >>= 1) r2 += __shfl_xor(r2, o);

    float qv = bz[lane] + Grow[Q0 + lane];
    #pragma unroll
    for (int r = 0; r < 8; ++r) {
        float a = Grow[U0 + r];
        float b = Grow[V0 + r];
        qv = fmaf(a * b, gout[r * 64 + lane], qv);
    }
    const float qorig = qv;

    const int ibase = (lane * (127 - lane)) / 2 - lane - 1;
    f32x2 m2[32];
    #pragma unroll
    for (int j = 0; j < 64; ++j) {
        const int jbase = (j * (127 - j)) / 2 - j - 1;
        int addr = (j > lane) ? (ibase + j) : (jbase + lane);
        addr = (j == lane) ? 0 : addr;
        float v = Vs[smp][addr];
        float val = (j > lane) ? v : -v;
        val = (j == lane) ? 0.0f : val;
        if (j & 1) m2[j >> 1].y = val; else m2[j >> 1].x = val;
    }

    float myinv = 0.0f;
    #pragma unroll
    for (int k = 0; k < 64; ++k) {
        const int kp = k >> 1;
        const float mk = (k & 1) ? m2[kp].y : m2[kp].x;
        float piv = rdlane(mk, k) + c;
        float inv = frcp(piv);
        bool isk = (lane == k);
        float f = isk ? 0.0f : mk * inv;
        myinv = isk ? inv : myinv;
        const float nf = -f;
        const f32x2 nf2 = {nf, nf};
        qv = fmaf(nf, rdlane(qv, k), qv);
        if ((k & 1) == 0)
            m2[kp].y = fmaf(nf, rdlane(m2[kp].y, k), m2[kp].y);
        #pragma unroll
        for (int p = kp + 1; p < 32; ++p) {
            f32x2 bc;
            bc.x = rdlane(m2[p].x, k);
            bc.y = rdlane(m2[p].y, k);
            m2[p] = __builtin_elementwise_fma(nf2, bc, m2[p]);
        }
        if (k & 1) m2[kp].y = f; else m2[kp].x = f;
    }
    float y = qv * myinv;

    // ---- one refinement step, f32 residual: r = (q - c*y) - S'*y
    float rf = fmaf(-c, y, qorig);
    #pragma unroll
    for (int j = 0; j < 64; ++j) {
        const int jbase = (j * (127 - j)) / 2 - j - 1;
        int addr = (j > lane) ? (ibase + j) : (jbase + lane);
        addr = (j == lane) ? 0 : addr;
        float v = Vs[smp][addr];
        float val = (j > lane) ? v : -v;
        val = (j == lane) ? 0.0f : val;
        rf = fmaf(-val, rdlane(y, j), rf);
    }
    #pragma unroll
    for (int k = 0; k < 64; ++k) {
        const float mk = (k & 1) ? m2[k >> 1].y : m2[k >> 1].x;
        rf = fmaf(-mk, rdlane(rf, k), rf);
    }
    y = fmaf(rf, myinv, y);

    const float v = 2.0f * c * y - qorig;

    float sc = 0.0f;
    const float4* cr = (const float4*)(cq + (size_t)lane * 64);
    #pragma unroll
    for (int j4 = 0; j4 < 16; ++j4) {
        float4 c4 = cr[j4];
        sc = fmaf(c4.x, rdlane(v, 4 * j4 + 0), sc);
        sc = fmaf(c4.y, rdlane(v, 4 * j4 + 1), sc);
        sc = fmaf(c4.z, rdlane(v, 4 * j4 + 2), sc);
        sc = fmaf(c4.w, rdlane(v, 4 * j4 + 3), sc);
    }

    float denom = fmaxf(1.0f - r2, 1e-3f);
    float tau   = fmaxf(4.0f * denom, 0.01f);
    float logit = sc * frcp(tau);
    float mx = logit;
    #pragma unroll
    for (int o = 32; o; o >>= 1) mx = fmaxf(mx, __shfl_xor(mx, o));
    float e = __expf(logit - mx);
    float sum = e;
    #pragma unroll
    for (int o = 32; o; o >>= 1) sum += __shfl_xor(sum, o);
    rw[s * 64 + lane] = e * frcp(sum);

    unsigned long long bal = __ballot(logit == mx);
    if (lane == 0) kc[s] = (float)(__ffsll(bal) - 1);
}

// ---------------- host orchestration (r15 config: single CB=32768 chunk)
extern "C" void kernel_launch(void* const* d_in, const int* in_sizes, int n_in,
                              void* d_out, int out_size, void* d_ws, size_t ws_size,
                              hipStream_t stream)
{
    const float* z    = (const float*)d_in[0];
    const float* wz   = (const float*)d_in[1];
    const float* bz   = (const float*)d_in[2];
    const float* gout = (const float*)d_in[3];
    const float* gu   = (const float*)d_in[4];
    const float* gv   = (const float*)d_in[5];
    const float* cq   = (const float*)d_in[6];
    const float* wt   = (const float*)d_in[7];

    float* rw = (float*)d_out;
    float* kc = rw + (size_t)B_N * NC_N;

    const size_t whl_b = (size_t)NP * KP * 2;   // ~6.7 MB
    int CB = 128;
    const int cands[9] = {32768, 16384, 8192, 4096, 2048, 1024, 512, 256, 128};
    for (int i = 0; i < 9; ++i) {
        size_t need = whl_b + (size_t)cands[i] * ((size_t)KP * 2 + (size_t)NP * 4);
        if (need <= ws_size) { CB = cands[i]; break; }
    }

    u16*   w_hl = (u16*)d_ws;
    u16*   z_hl = (u16*)((char*)d_ws + whl_b);
    float* G    = (float*)((char*)d_ws + whl_b + (size_t)CB * KP * 2);

    prep_w_kernel<<<NP / 2, 256, 0, stream>>>(wt, wz, gu, gv, w_hl);
    for (int cs = 0; cs < B_N; cs += CB) {
        prep_z_kernel<<<CB / 2, 256, 0, stream>>>(z, z_hl, cs, CB);
        gemm_kernel<<<dim3(NP / 128, CB / 128), 256, 0, stream>>>(z_hl, w_hl, G);
        solve_kernel<<<CB / 4, 256, 0, stream>>>(z, bz, gout, cq, G, rw, kc, cs);
    }
}